// Round 18
// baseline (408.661 us; speedup 1.0000x reference)
//
#include <hip/hip_runtime.h>

#define CCH 384
#define HH 192
#define WWD 192
#define NIMG 2
#define HWP (HH * WWD)        // 36864 pixels per image
#define PTOT (NIMG * HWP)     // 73728
#define HEADS 12
#define HD 32
#define NWIN 24
#define WINS 576              // windows per image
#define EELEM ((size_t)NIMG * CCH * HWP)   // elems per tensor (28,311,552)
#define WMAT 147456           // 384*384

typedef __attribute__((ext_vector_type(8))) short bh8;            // 8 bf16 (MFMA frag)
typedef __attribute__((ext_vector_type(8))) unsigned short us8;
typedef __attribute__((ext_vector_type(4))) unsigned short us4;
typedef __attribute__((ext_vector_type(4))) float fx4;

__device__ __forceinline__ unsigned short f2bf(float f) {
    unsigned u = __float_as_uint(f);
    u += 0x7fffu + ((u >> 16) & 1u);      // round-to-nearest-even
    return (unsigned short)(u >> 16);
}

__device__ __forceinline__ void gload16(const void* g, void* l) {
    __builtin_amdgcn_global_load_lds(
        (const __attribute__((address_space(1))) void*)g,
        (__attribute__((address_space(3))) void*)l, 16, 0, 0);
}

// ---------------------------------------------------------------------------
// prep (merged): [0,288) pw weights->bf16; [288,329) dw weight transpose;
// [329,521) rel-pos bias expansion, LANE-COALESCED layout:
//   Bx[h][li][g][nf][mf][r]  (per attn-lane contiguous 256 B run)
// ---------------------------------------------------------------------------
__global__ __launch_bounds__(256) void prep(
    const float* __restrict__ qp, const float* __restrict__ kp,
    const float* __restrict__ vp, const float* __restrict__ pj,
    const float* __restrict__ qd, const float* __restrict__ kd,
    const float* __restrict__ vd, const float* __restrict__ rpb,
    unsigned short* __restrict__ Wb, float* __restrict__ dwT,
    float* __restrict__ Bx)
{
    int bx = blockIdx.x;
    if (bx < 288) {
        int idx8 = (bx * 256 + threadIdx.x) * 8;
        int which = idx8 / WMAT;
        int loc = idx8 - which * WMAT;
        const float* s = (which == 0) ? qp : (which == 1) ? kp : (which == 2) ? vp : pj;
        float4 v0 = *(const float4*)(s + loc);
        float4 v1 = *(const float4*)(s + loc + 4);
        us8 ov;
        ov[0] = f2bf(v0.x); ov[1] = f2bf(v0.y); ov[2] = f2bf(v0.z); ov[3] = f2bf(v0.w);
        ov[4] = f2bf(v1.x); ov[5] = f2bf(v1.y); ov[6] = f2bf(v1.z); ov[7] = f2bf(v1.w);
        *(us8*)(Wb + idx8) = ov;
    } else if (bx < 329) {
        int idx = (bx - 288) * 256 + threadIdx.x;
        if (idx < 3 * 9 * CCH) {
            int ten = idx / (9 * CCH);
            int rem = idx - ten * (9 * CCH);
            int tap = rem / CCH;
            int c   = rem - tap * CCH;
            const float* s = (ten == 0) ? qd : (ten == 1) ? kd : vd;
            dwT[idx] = s[c * 9 + tap];
        }
    } else {
        int idx = (bx - 329) * 256 + threadIdx.x;   // 192*256 = 49152 exact
        int h    = idx >> 12;
        int rem  = idx & 4095;
        int li   = rem >> 8;
        int rem2 = rem & 255;
        int g    = rem2 >> 6;
        int rem3 = rem2 & 63;
        int nf   = rem3 >> 4;
        int rem4 = rem3 & 15;
        int mf   = rem4 >> 2;
        int r    = rem4 & 3;
        int tk = nf * 16 + li;
        int tq = mf * 16 + g * 4 + r;
        int dy = (tq >> 3) - (tk >> 3) + 7;
        int dx = (tq & 7) - (tk & 7) + 7;
        Bx[idx] = rpb[(dy * 15 + dx) * HEADS + h];
    }
}

// ---------------------------------------------------------------------------
// FUSED depthwise 3x3 + bias + window-gather transpose (v9: split-stage T14).
// Same geometry as proven v7 (6912 blocks, 64ch/block, odd-121 halo stride),
// but channels split into two 32-ch subchunks A/B: issue A+B global loads
// into regs, ds_write A, barrier, COMPUTE A while B's loads are in flight,
// ds_write B, barrier, compute B. Hides one stage round-trip per block.
// Thread = 1 channel x 1 pixel row (8 px) per subchunk.
// ---------------------------------------------------------------------------
__global__ __launch_bounds__(256) void dwgather(
    const float* __restrict__ x,
    const float* __restrict__ wt,       // [3][9][384] fp32 transposed dw weights
    const float* __restrict__ qb, const float* __restrict__ kb,
    const float* __restrict__ vb,
    unsigned short* __restrict__ oq, unsigned short* __restrict__ ok,
    unsigned short* __restrict__ ov)
{
    __shared__ float halo[2][32 * 121];     // 30.25 KB

    // bijective XCD swizzle: 6912 = 8 * 864
    int bid = blockIdx.x;
    int b = (bid & 7) * 864 + (bid >> 3);
    int wtx  = b % 24;
    int strip = b / 24;                     // 0..287
    int chv  = strip % 6;
    int nwy  = strip / 6;                   // 0..47
    int wy   = nwy % 24;
    int n    = nwy / 24;

    int h0 = wy * 8, w0 = wtx * 8;
    int tid = threadIdx.x;
    int c   = tid & 31;                     // channel within 32-subchunk
    int pxg = tid >> 5;                     // 0..7 pixel row
    int cgA = chv * 64 + c;
    int cgB = cgA + 32;
    int widx = n * WINS + wy * NWIN + wtx;

    const float* xbA = x + (size_t)n * CCH * HWP + (size_t)(chv * 64) * HWP;
    const float* xbB = xbA + (size_t)32 * HWP;

    // ---- A weights (needed first) ----
    float wqA[9], wkA[9], wvA[9];
#pragma unroll
    for (int t = 0; t < 9; ++t) {
        wqA[t] = wt[t * CCH + cgA];
        wkA[t] = wt[9 * CCH + t * CCH + cgA];
        wvA[t] = wt[18 * CCH + t * CCH + cgA];
    }
    float bqA = qb[cgA], bkA = kb[cgA], bvA = vb[cgA];

    // ---- issue A halo loads -> regs (960 jobs: 32ch x 10r x 3seg) ----
    float4 regA[4], regB[4];
#pragma unroll
    for (int it = 0; it < 4; ++it) {
        int j = it * 256 + tid;
        float4 val = make_float4(0.f, 0.f, 0.f, 0.f);
        if (j < 960) {
            int seg = j % 3;
            int t   = j / 3;
            int rr  = t % 10;
            int cc  = t / 10;
            int hr  = h0 - 1 + rr;
            int cb  = w0 - 2 + seg * 4;
            if (hr >= 0 && hr < HH) {
                const float* p = xbA + (size_t)cc * HWP + (size_t)hr * WWD;
                if (cb >= 0 && cb + 4 <= WWD) {
                    val = *(const float4*)(p + cb);
                } else {
                    if (cb + 0 >= 0 && cb + 0 < WWD) val.x = p[cb + 0];
                    if (cb + 1 >= 0 && cb + 1 < WWD) val.y = p[cb + 1];
                    if (cb + 2 >= 0 && cb + 2 < WWD) val.z = p[cb + 2];
                    if (cb + 3 >= 0 && cb + 3 < WWD) val.w = p[cb + 3];
                }
            }
        }
        regA[it] = val;
    }
    // ---- issue B halo loads -> regs ----
#pragma unroll
    for (int it = 0; it < 4; ++it) {
        int j = it * 256 + tid;
        float4 val = make_float4(0.f, 0.f, 0.f, 0.f);
        if (j < 960) {
            int seg = j % 3;
            int t   = j / 3;
            int rr  = t % 10;
            int cc  = t / 10;
            int hr  = h0 - 1 + rr;
            int cb  = w0 - 2 + seg * 4;
            if (hr >= 0 && hr < HH) {
                const float* p = xbB + (size_t)cc * HWP + (size_t)hr * WWD;
                if (cb >= 0 && cb + 4 <= WWD) {
                    val = *(const float4*)(p + cb);
                } else {
                    if (cb + 0 >= 0 && cb + 0 < WWD) val.x = p[cb + 0];
                    if (cb + 1 >= 0 && cb + 1 < WWD) val.y = p[cb + 1];
                    if (cb + 2 >= 0 && cb + 2 < WWD) val.z = p[cb + 2];
                    if (cb + 3 >= 0 && cb + 3 < WWD) val.w = p[cb + 3];
                }
            }
        }
        regB[it] = val;
    }
    // ---- issue B weights (land during compute A) ----
    float wqB[9], wkB[9], wvB[9];
#pragma unroll
    for (int t = 0; t < 9; ++t) {
        wqB[t] = wt[t * CCH + cgB];
        wkB[t] = wt[9 * CCH + t * CCH + cgB];
        wvB[t] = wt[18 * CCH + t * CCH + cgB];
    }
    float bqB = qb[cgB], bkB = kb[cgB], bvB = vb[cgB];

    // ---- ds_write A (compiler waits only on regA's loads) ----
#pragma unroll
    for (int it = 0; it < 4; ++it) {
        int j = it * 256 + tid;
        if (j < 960) {
            int seg = j % 3;
            int t   = j / 3;
            int rr  = t % 10;
            int cc  = t / 10;
            int hb  = cc * 121 + rr * 12 + seg * 4;
            halo[0][hb + 0] = regA[it].x;
            halo[0][hb + 1] = regA[it].y;
            halo[0][hb + 2] = regA[it].z;
            halo[0][hb + 3] = regA[it].w;
        }
    }
    __syncthreads();

    // ---- compute A: row pxg, channel cgA (B loads still in flight) ----
    {
        const int hb0 = c * 121 + pxg * 12;
        float r0[10], r1[10], r2[10];
#pragma unroll
        for (int cc = 0; cc < 10; ++cc) r0[cc] = halo[0][hb0 + cc + 1];
#pragma unroll
        for (int cc = 0; cc < 10; ++cc) r1[cc] = halo[0][hb0 + 12 + cc + 1];
#pragma unroll
        for (int cc = 0; cc < 10; ++cc) r2[cc] = halo[0][hb0 + 24 + cc + 1];
        size_t ob0 = ((size_t)widx * 64 + pxg * 8) * CCH + cgA;
#pragma unroll
        for (int pc = 0; pc < 8; ++pc) {
            float sq = 0.f, sk = 0.f, sv = 0.f;
#pragma unroll
            for (int dc = 0; dc < 3; ++dc) {
                float x0 = r0[pc + dc], x1 = r1[pc + dc], x2 = r2[pc + dc];
                sq = fmaf(x0, wqA[dc], sq);     sk = fmaf(x0, wkA[dc], sk);     sv = fmaf(x0, wvA[dc], sv);
                sq = fmaf(x1, wqA[3 + dc], sq); sk = fmaf(x1, wkA[3 + dc], sk); sv = fmaf(x1, wvA[3 + dc], sv);
                sq = fmaf(x2, wqA[6 + dc], sq); sk = fmaf(x2, wkA[6 + dc], sk); sv = fmaf(x2, wvA[6 + dc], sv);
            }
            size_t o = ob0 + (size_t)pc * CCH;
            oq[o] = f2bf(sq + bqA);
            ok[o] = f2bf(sk + bkA);
            ov[o] = f2bf(sv + bvA);
        }
    }

    // ---- ds_write B, barrier, compute B ----
#pragma unroll
    for (int it = 0; it < 4; ++it) {
        int j = it * 256 + tid;
        if (j < 960) {
            int seg = j % 3;
            int t   = j / 3;
            int rr  = t % 10;
            int cc  = t / 10;
            int hb  = cc * 121 + rr * 12 + seg * 4;
            halo[1][hb + 0] = regB[it].x;
            halo[1][hb + 1] = regB[it].y;
            halo[1][hb + 2] = regB[it].z;
            halo[1][hb + 3] = regB[it].w;
        }
    }
    __syncthreads();

    {
        const int hb0 = c * 121 + pxg * 12;
        float r0[10], r1[10], r2[10];
#pragma unroll
        for (int cc = 0; cc < 10; ++cc) r0[cc] = halo[1][hb0 + cc + 1];
#pragma unroll
        for (int cc = 0; cc < 10; ++cc) r1[cc] = halo[1][hb0 + 12 + cc + 1];
#pragma unroll
        for (int cc = 0; cc < 10; ++cc) r2[cc] = halo[1][hb0 + 24 + cc + 1];
        size_t ob0 = ((size_t)widx * 64 + pxg * 8) * CCH + cgB;
#pragma unroll
        for (int pc = 0; pc < 8; ++pc) {
            float sq = 0.f, sk = 0.f, sv = 0.f;
#pragma unroll
            for (int dc = 0; dc < 3; ++dc) {
                float x0 = r0[pc + dc], x1 = r1[pc + dc], x2 = r2[pc + dc];
                sq = fmaf(x0, wqB[dc], sq);     sk = fmaf(x0, wkB[dc], sk);     sv = fmaf(x0, wvB[dc], sv);
                sq = fmaf(x1, wqB[3 + dc], sq); sk = fmaf(x1, wkB[3 + dc], sk); sv = fmaf(x1, wvB[3 + dc], sv);
                sq = fmaf(x2, wqB[6 + dc], sq); sk = fmaf(x2, wkB[6 + dc], sk); sv = fmaf(x2, wvB[6 + dc], sv);
            }
            size_t o = ob0 + (size_t)pc * CCH;
            oq[o] = f2bf(sq + bqB);
            ok[o] = f2bf(sk + bkB);
            ov[o] = f2bf(sv + bvB);
        }
    }
}

// issue macro shared by both GEMMs: one K-tile (4 gload16 per wave)
#define ISSUE_TILE(KT, BUF)                                                     \
    do {                                                                        \
        int k0_ = (KT) * 32;                                                    \
        gload16(Wg0 + k0_,                     &Wt[BUF][wid * 32][0]);          \
        gload16(Wg0 + (size_t)16 * CCH + k0_,  &Wt[BUF][wid * 32 + 16][0]);     \
        gload16(Yg0 + k0_,                     &Yt[BUF][wid * 32][0]);          \
        gload16(Yg0 + (size_t)16 * CCH + k0_,  &Yt[BUF][wid * 32 + 16][0]);     \
    } while (0)

// ---------------------------------------------------------------------------
// MERGED q/k/v bf16 MFMA GEMM, depth-2 counted-vmcnt pipeline (T4) with
// register-preloaded bias (exact vmcnt ledger). No setprio (GEMM-null, m190).
// ---------------------------------------------------------------------------
__global__ __launch_bounds__(256) void qkv_gemm(
    const unsigned short* __restrict__ tr0, const unsigned short* __restrict__ tr1,
    const unsigned short* __restrict__ tr2, const unsigned short* __restrict__ Wball,
    const float* __restrict__ qpb, const float* __restrict__ kpb,
    const float* __restrict__ vpb, float scale,
    unsigned short* __restrict__ qo, unsigned short* __restrict__ ko,
    unsigned short* __restrict__ vo)
{
    __shared__ __align__(16) char smem[49152];   // staging [3] bufs U epilogue T16
    typedef unsigned short (*tile3)[128][32];
    tile3 Wt = (tile3)smem;                      // [3][128][32]
    tile3 Yt = (tile3)(smem + 24576);
    typedef unsigned short (*tep_t)[132];
    tep_t T16 = (tep_t)smem;

    // decode: O = tensor-major, then p-tile, c-tile innermost (L2 reuse of Y)
    int bL = blockIdx.x;
    int O  = (bL & 7) * 648 + (bL >> 3);
    int z  = O / 1728;
    int rem = O - z * 1728;
    int py = rem / 3;
    int cx = rem - py * 3;
    int pp0 = py * 128, cm0 = cx * 128;

    const unsigned short* Y  = (z == 0) ? tr0 : (z == 1) ? tr1 : tr2;
    const unsigned short* Wb = Wball + (size_t)z * WMAT;
    const float* bias        = (z == 0) ? qpb : (z == 1) ? kpb : vpb;
    float sc                 = (z == 0) ? scale : 1.0f;
    unsigned short* outb     = (z == 0) ? qo : (z == 1) ? ko : vo;
    bool vmode = (z == 2);

    int tid = threadIdx.x;
    int lid = tid & 63, wid = tid >> 6;
    int wr = wid >> 1, wc = wid & 1;
    int li = lid & 15, g = lid >> 4;

    // staging: srow 0..15 in 16-row group; SOURCE slot pre-swizzled
    int srow = (lid >> 2);
    int scol = (((lid & 3) ^ ((srow >> 1) & 3))) * 8;
    // read-side swizzled k-slot (row base multiples of 16 -> depends on li only)
    int gsw = (g ^ ((li >> 1) & 3)) * 8;

    fx4 acc[4][4];
#pragma unroll
    for (int i = 0; i < 4; ++i)
#pragma unroll
        for (int j = 0; j < 4; ++j) acc[i][j] = (fx4){0.f, 0.f, 0.f, 0.f};

    tile3 A3 = vmode ? Yt : Wt;          // block-uniform select
    tile3 B3 = vmode ? Wt : Yt;

    const unsigned short* Wg0 = Wb + (size_t)(cm0 + wid * 32 + srow) * CCH + scol;
    const unsigned short* Yg0 = Y  + (size_t)(pp0 + wid * 32 + srow) * CCH + scol;

    // ---- preload epilogue bias to registers, DRAIN, so loop vmcnt is exact --
    float4 bv4[4];
    float  bvs[4];
    if (!vmode) {
#pragma unroll
        for (int mf = 0; mf < 4; ++mf)
            bv4[mf] = *(const float4*)&bias[cm0 + wr * 64 + mf * 16 + g * 4];
    } else {
#pragma unroll
        for (int nf = 0; nf < 4; ++nf)
            bvs[nf] = bias[cm0 + wc * 64 + nf * 16 + li];
    }
    asm volatile("s_waitcnt vmcnt(0)" ::: "memory");
    __builtin_amdgcn_sched_barrier(0);

    ISSUE_TILE(0, 0);
    ISSUE_TILE(1, 1);

#pragma unroll
    for (int kt = 0; kt < 12; ++kt) {
        __builtin_amdgcn_sched_barrier(0);
        if (kt < 11) asm volatile("s_waitcnt vmcnt(4)" ::: "memory");
        else         asm volatile("s_waitcnt vmcnt(0)" ::: "memory");
        __builtin_amdgcn_s_barrier();            // raw: no implicit drain
        __builtin_amdgcn_sched_barrier(0);
        if (kt < 10) ISSUE_TILE(kt + 2, (kt + 2) % 3);

        int cur = kt % 3;
        bh8 a[4], b[4];
#pragma unroll
        for (int mf = 0; mf < 4; ++mf)
            a[mf] = *(const bh8*)&A3[cur][wr * 64 + mf * 16 + li][gsw];
#pragma unroll
        for (int nf = 0; nf < 4; ++nf)
            b[nf] = *(const bh8*)&B3[cur][wc * 64 + nf * 16 + li][gsw];
#pragma unroll
        for (int mf = 0; mf < 4; ++mf)
#pragma unroll
            for (int nf = 0; nf < 4; ++nf)
                acc[mf][nf] = __builtin_amdgcn_mfma_f32_16x16x32_bf16(
                    a[mf], b[nf], acc[mf][nf], 0, 0, 0);
    }

    __syncthreads();                     // staging dead; safe to overwrite w/ T16

    if (!vmode) {
        // D rows = c (A=W), cols = p. T16[p_local][c_local]; out [p][c].
#pragma unroll
        for (int mf = 0; mf < 4; ++mf) {
            int cl = wr * 64 + mf * 16 + g * 4;
            float4 bv = bv4[mf];
#pragma unroll
            for (int nf = 0; nf < 4; ++nf) {
                int pl = wc * 64 + nf * 16 + li;
                us4 o;
                o[0] = f2bf((acc[mf][nf][0] + bv.x) * sc);
                o[1] = f2bf((acc[mf][nf][1] + bv.y) * sc);
                o[2] = f2bf((acc[mf][nf][2] + bv.z) * sc);
                o[3] = f2bf((acc[mf][nf][3] + bv.w) * sc);
                *(us4*)&T16[pl][cl] = o;
            }
        }
        __syncthreads();
#pragma unroll
        for (int it = 0; it < 8; ++it) {
            int row = it * 16 + wid * 4 + (lid >> 4);
            int col = (lid & 15) * 8;
            us8 vv = *(const us8*)&T16[row][col];
            *(us8*)(outb + (size_t)(pp0 + row) * CCH + cm0 + col) = vv;
        }
    } else {
        // D rows = p (A=Y), cols = c. T16[c_local][p_local]; out [n][c][p_l].
#pragma unroll
        for (int nf = 0; nf < 4; ++nf) {
            int cl = wc * 64 + nf * 16 + li;
            float bv = bvs[nf];
#pragma unroll
            for (int mf = 0; mf < 4; ++mf) {
                int pl = wr * 64 + mf * 16 + g * 4;
                us4 o;
                o[0] = f2bf(acc[mf][nf][0] + bv);
                o[1] = f2bf(acc[mf][nf][1] + bv);
                o[2] = f2bf(acc[mf][nf][2] + bv);
                o[3] = f2bf(acc[mf][nf][3] + bv);
                *(us4*)&T16[cl][pl] = o;
            }
        }
        __syncthreads();
        int n = pp0 / HWP;
        int pl0 = pp0 - n * HWP;
#pragma unroll
        for (int it = 0; it < 8; ++it) {
            int row = it * 16 + wid * 4 + (lid >> 4);   // c_local
            int col = (lid & 15) * 8;                   // p_local
            us8 vv = *(const us8*)&T16[row][col];
            *(us8*)(outb + (size_t)(n * CCH + cm0 + row) * HWP + pl0 + col) = vv;
        }
    }
}

// ---------------------------------------------------------------------------
// proj GEMM: depth-2 counted-vmcnt pipeline with preloaded+drained bias;
// direct fp32 scatter stores. 1-D grid 1728 = 8 x 216, c-tile innermost.
// ---------------------------------------------------------------------------
__global__ __launch_bounds__(256) void proj_gemm(
    const unsigned short* __restrict__ Y, const unsigned short* __restrict__ Wb,
    const float* __restrict__ bias, float* __restrict__ outf)
{
    __shared__ unsigned short Wt[3][128][32];
    __shared__ unsigned short Yt[3][128][32];

    int bL = blockIdx.x;
    int O  = (bL & 7) * 216 + (bL >> 3);
    int py = O / 3;
    int cx = O - py * 3;
    int pp0 = py * 128, cm0 = cx * 128;

    int tid = threadIdx.x;
    int lid = tid & 63, wid = tid >> 6;
    int wr = wid >> 1, wc = wid & 1;
    int li = lid & 15, g = lid >> 4;

    int srow = (lid >> 2);
    int scol = (((lid & 3) ^ ((srow >> 1) & 3))) * 8;
    int gsw = (g ^ ((li >> 1) & 3)) * 8;

    fx4 acc[4][4];
#pragma unroll
    for (int i = 0; i < 4; ++i)
#pragma unroll
        for (int j = 0; j < 4; ++j) acc[i][j] = (fx4){0.f, 0.f, 0.f, 0.f};

    const unsigned short* Wg0 = Wb + (size_t)(cm0 + wid * 32 + srow) * CCH + scol;
    const unsigned short* Yg0 = Y  + (size_t)(pp0 + wid * 32 + srow) * CCH + scol;

    // preload bias (float4 per mf), drain so loop vmcnt ledger is exact
    float4 bv4[4];
#pragma unroll
    for (int mf = 0; mf < 4; ++mf)
        bv4[mf] = *(const float4*)&bias[cm0 + wr * 64 + mf * 16 + g * 4];
    asm volatile("s_waitcnt vmcnt(0)" ::: "memory");
    __builtin_amdgcn_sched_barrier(0);

    ISSUE_TILE(0, 0);
    ISSUE_TILE(1, 1);

#pragma unroll
    for (int kt = 0; kt < 12; ++kt) {
        __builtin_amdgcn_sched_barrier(0);
        if (kt < 11) asm volatile("s_waitcnt vmcnt(4)" ::: "memory");
        else         asm volatile("s_waitcnt vmcnt(0)" ::: "memory");
        __builtin_amdgcn_s_barrier();
        __builtin_amdgcn_sched_barrier(0);
        if (kt < 10) ISSUE_TILE(kt + 2, (kt + 2) % 3);

        int cur = kt % 3;
        bh8 a[4], b[4];
#pragma unroll
        for (int mf = 0; mf < 4; ++mf)
            a[mf] = *(const bh8*)&Wt[cur][wr * 64 + mf * 16 + li][gsw];
#pragma unroll
        for (int nf = 0; nf < 4; ++nf)
            b[nf] = *(const bh8*)&Yt[cur][wc * 64 + nf * 16 + li][gsw];
#pragma unroll
        for (int mf = 0; mf < 4; ++mf)
#pragma unroll
            for (int nf = 0; nf < 4; ++nf)
                acc[mf][nf] = __builtin_amdgcn_mfma_f32_16x16x32_bf16(
                    a[mf], b[nf], acc[mf][nf], 0, 0, 0);
    }

    // D rows = c, cols = p (lane). fp32 std layout, un-gather windows.
#pragma unroll
    for (int mf = 0; mf < 4; ++mf) {
        int c = cm0 + wr * 64 + mf * 16 + g * 4;
#pragma unroll
        for (int nf = 0; nf < 4; ++nf) {
            int p = pp0 + wc * 64 + nf * 16 + li;
            int n = p / HWP;
            int rem = p - n * HWP;
            int win = rem >> 6, t = rem & 63;
            int h = (win / NWIN) * 8 + (t >> 3);
            int w = (win % NWIN) * 8 + (t & 7);
            float* op = outf + (size_t)n * CCH * HWP + (size_t)h * WWD + w;
            op[(size_t)(c + 0) * HWP] = acc[mf][nf][0] + bv4[mf].x;
            op[(size_t)(c + 1) * HWP] = acc[mf][nf][1] + bv4[mf].y;
            op[(size_t)(c + 2) * HWP] = acc[mf][nf][2] + bv4[mf].z;
            op[(size_t)(c + 3) * HWP] = acc[mf][nf][3] + bv4[mf].w;
        }
    }
}

// ---------------------------------------------------------------------------
// MFMA window attention v3: wave = ONE (window, head) pair; grid 3456 = 8x432.
// Bx lane-coalesced [h][li][g][nf][mf][4]; Pl halved [4][64][36].
// ---------------------------------------------------------------------------
__global__ __launch_bounds__(256) void attn(
    const unsigned short* __restrict__ q, const unsigned short* __restrict__ k,
    const unsigned short* __restrict__ v, const float* __restrict__ Bx,
    unsigned short* __restrict__ o)
{
    __shared__ unsigned short Pl[4][64][36];

    int tid = threadIdx.x, lid = tid & 63, wid = tid >> 6;
    int bL = blockIdx.x;
    int b = (bL & 7) * 432 + (bL >> 3);     // bijective XCD swizzle
    int pair = b * 4 + wid;                 // 0..13823
    int wl = pair / 12;
    int hq = pair - wl * 12;
    int n = wl / WINS, winl = wl - n * WINS;
    int li = lid & 15, g = lid >> 4;

    const fx4 z = (fx4){0.f, 0.f, 0.f, 0.f};

    const unsigned short* qp = q + (size_t)(wl * 64) * CCH + hq * HD + g * 8;
    const unsigned short* kp = k + (size_t)(wl * 64) * CCH + hq * HD + g * 8;
    bh8 aq[4], bk[4];
#pragma unroll
    for (int mf = 0; mf < 4; ++mf)
        aq[mf] = *(const bh8*)(qp + (size_t)(mf * 16 + li) * CCH);
#pragma unroll
    for (int nf = 0; nf < 4; ++nf)
        bk[nf] = *(const bh8*)(kp + (size_t)(nf * 16 + li) * CCH);

    // hoisted V loads (independent): softmax covers their latency
    bh8 av2[2][2];
#pragma unroll
    for (int ks = 0; ks < 2; ++ks)
#pragma unroll
        for (int m2 = 0; m2 < 2; ++m2)
            av2[ks][m2] = *(const bh8*)(v + (size_t)(n * CCH + hq * HD + m2 * 16 + li) * HWP
                                          + winl * 64 + ks * 32 + g * 8);

    fx4 s[4][4];
    __builtin_amdgcn_s_setprio(1);
#pragma unroll
    for (int mf = 0; mf < 4; ++mf)
#pragma unroll
        for (int nf = 0; nf < 4; ++nf)
            s[mf][nf] = __builtin_amdgcn_mfma_f32_16x16x32_bf16(aq[mf], bk[nf], z, 0, 0, 0);
    __builtin_amdgcn_s_setprio(0);

    // bias: lane-coalesced table, per-lane contiguous 256 B
    {
        const float* bxl = Bx + (((size_t)hq * 16 + li) * 4 + g) * 64;
#pragma unroll
        for (int nf = 0; nf < 4; ++nf)
#pragma unroll
            for (int mf = 0; mf < 4; ++mf) {
                fx4 bv = *(const fx4*)&bxl[(nf * 4 + mf) * 4];
                s[mf][nf] += bv;
            }
    }

    // softmax across tk (lane group of 16 shares a row set)
    float inv_[4][4];
#pragma unroll
    for (int mf = 0; mf < 4; ++mf)
#pragma unroll
        for (int r = 0; r < 4; ++r) {
            float m = s[mf][0][r];
#pragma unroll
            for (int nf = 1; nf < 4; ++nf) m = fmaxf(m, s[mf][nf][r]);
            m = fmaxf(m, __shfl_xor(m, 1));
            m = fmaxf(m, __shfl_xor(m, 2));
            m = fmaxf(m, __shfl_xor(m, 4));
            m = fmaxf(m, __shfl_xor(m, 8));
            float sum = 0.f;
#pragma unroll
            for (int nf = 0; nf < 4; ++nf) {
                float e = __expf(s[mf][nf][r] - m);
                s[mf][nf][r] = e;
                sum += e;
            }
            sum += __shfl_xor(sum, 1);
            sum += __shfl_xor(sum, 2);
            sum += __shfl_xor(sum, 4);
            sum += __shfl_xor(sum, 8);
            inv_[mf][r] = 1.f / sum;
        }

    // O^T = V^T x P^T : D[d][tq], P processed per tk-half through halved Pl
    fx4 o2[2][4];
#pragma unroll
    for (int m2 = 0; m2 < 2; ++m2)
#pragma unroll
        for (int nf = 0; nf < 4; ++nf) o2[m2][nf] = z;

#pragma unroll
    for (int ks = 0; ks < 2; ++ks) {
        // write this tk-half of P (tk = ks*32 + nf2*16 + li)
#pragma unroll
        for (int mf = 0; mf < 4; ++mf)
#pragma unroll
            for (int nf2 = 0; nf2 < 2; ++nf2) {
                int nf = ks * 2 + nf2;
#pragma unroll
                for (int r = 0; r < 4; ++r)
                    Pl[wid][mf * 16 + g * 4 + r][nf2 * 16 + li] =
                        f2bf(s[mf][nf][r] * inv_[mf][r]);
            }
        // read B-fragments (tq-block nfq, k-slice within half) and accumulate
        bh8 bp[4];
#pragma unroll
        for (int nfq = 0; nfq < 4; ++nfq)
            bp[nfq] = *(const bh8*)&Pl[wid][nfq * 16 + li][g * 8];
        __builtin_amdgcn_s_setprio(1);
#pragma unroll
        for (int m2 = 0; m2 < 2; ++m2)
#pragma unroll
            for (int nfq = 0; nfq < 4; ++nfq)
                o2[m2][nfq] = __builtin_amdgcn_mfma_f32_16x16x32_bf16(
                    av2[ks][m2], bp[nfq], o2[m2][nfq], 0, 0, 0);
        __builtin_amdgcn_s_setprio(0);
    }

#pragma unroll
    for (int nf = 0; nf < 4; ++nf) {
        int tq = nf * 16 + li;
#pragma unroll
        for (int m2 = 0; m2 < 2; ++m2) {
            int d = hq * HD + m2 * 16 + g * 4;
            us4 ov;
            ov[0] = f2bf(o2[m2][nf][0]);
            ov[1] = f2bf(o2[m2][nf][1]);
            ov[2] = f2bf(o2[m2][nf][2]);
            ov[3] = f2bf(o2[m2][nf][3]);
            *(us4*)(o + (size_t)(wl * 64 + tq) * CCH + d) = ov;
        }
    }
}

// ---------------------------------------------------------------------------
extern "C" void kernel_launch(void* const* d_in, const int* in_sizes, int n_in,
                              void* d_out, int out_size, void* d_ws, size_t ws_size,
                              hipStream_t stream) {
    const float* vid  = (const float*)d_in[0];
    const float* qd_w = (const float*)d_in[1];
    const float* qd_b = (const float*)d_in[2];
    const float* qp_w = (const float*)d_in[3];
    const float* qp_b = (const float*)d_in[4];
    const float* kd_w = (const float*)d_in[5];
    const float* kd_b = (const float*)d_in[6];
    const float* kp_w = (const float*)d_in[7];
    const float* kp_b = (const float*)d_in[8];
    const float* vd_w = (const float*)d_in[9];
    const float* vd_b = (const float*)d_in[10];
    const float* vp_w = (const float*)d_in[11];
    const float* vp_b = (const float*)d_in[12];
    const float* rpb  = (const float*)d_in[13];
    const float* pj_w = (const float*)d_in[14];
    const float* pj_b = (const float*)d_in[15];

    unsigned short* ws16 = (unsigned short*)d_ws;
    unsigned short* tr0 = ws16 + 3 * EELEM;     // [p_wg][c] bf16 (q,k,v pre-GEMM)
    unsigned short* tr1 = ws16 + 4 * EELEM;
    unsigned short* tr2 = ws16 + 5 * EELEM;
    unsigned short* Wb  = ws16 + 6 * EELEM;     // 4 x 147456 bf16
    float* dwT          = (float*)(Wb + 4 * WMAT);      // [3][9][384] fp32
    float* Bx           = dwT + 3 * 9 * CCH;            // [12][16][4][4][4][4] fp32
    unsigned short* qb  = ws16;                 // post-GEMM q,k,v
    unsigned short* kb  = ws16 + EELEM;
    unsigned short* vb  = ws16 + 2 * EELEM;
    unsigned short* ob  = tr0;                  // attn out reuses tr region

    prep<<<521, 256, 0, stream>>>(qp_w, kp_w, vp_w, pj_w,
                                  qd_w, kd_w, vd_w, rpb, Wb, dwT, Bx);
    dwgather<<<NIMG * WINS * 6, 256, 0, stream>>>(
        vid, dwT, qd_b, kd_b, vd_b, tr0, tr1, tr2);

    const float scale = 0.17677669529663687f;   // 32^-0.5 folded into q
    qkv_gemm<<<5184, 256, 0, stream>>>(
        tr0, tr1, tr2, Wb, qp_b, kp_b, vp_b, scale, qb, kb, vb);

    attn<<<3456, 256, 0, stream>>>(qb, kb, vb, Bx, ob);

    proj_gemm<<<1728, 256, 0, stream>>>(
        ob, Wb + 3 * WMAT, pj_b, (float*)d_out);
}

// Round 19
// 381.933 us; speedup vs baseline: 1.0700x; 1.0700x over previous
//
#include <hip/hip_runtime.h>

#define CCH 384
#define HH 192
#define WWD 192
#define NIMG 2
#define HWP (HH * WWD)        // 36864 pixels per image
#define PTOT (NIMG * HWP)     // 73728
#define HEADS 12
#define HD 32
#define NWIN 24
#define WINS 576              // windows per image
#define EELEM ((size_t)NIMG * CCH * HWP)   // elems per tensor (28,311,552)
#define WMAT 147456           // 384*384

typedef __attribute__((ext_vector_type(8))) short bh8;            // 8 bf16 (MFMA frag)
typedef __attribute__((ext_vector_type(8))) unsigned short us8;
typedef __attribute__((ext_vector_type(4))) unsigned short us4;
typedef __attribute__((ext_vector_type(4))) float fx4;

__device__ __forceinline__ unsigned short f2bf(float f) {
    unsigned u = __float_as_uint(f);
    u += 0x7fffu + ((u >> 16) & 1u);      // round-to-nearest-even
    return (unsigned short)(u >> 16);
}

__device__ __forceinline__ void gload16(const void* g, void* l) {
    __builtin_amdgcn_global_load_lds(
        (const __attribute__((address_space(1))) void*)g,
        (__attribute__((address_space(3))) void*)l, 16, 0, 0);
}

// ---------------------------------------------------------------------------
// prep (merged): [0,288) pw weights->bf16; [288,329) dw weight transpose;
// [329,521) rel-pos bias expansion, LANE-COALESCED layout:
//   Bx[h][li][g][nf][mf][r]  (per attn-lane contiguous 256 B run)
// ---------------------------------------------------------------------------
__global__ __launch_bounds__(256) void prep(
    const float* __restrict__ qp, const float* __restrict__ kp,
    const float* __restrict__ vp, const float* __restrict__ pj,
    const float* __restrict__ qd, const float* __restrict__ kd,
    const float* __restrict__ vd, const float* __restrict__ rpb,
    unsigned short* __restrict__ Wb, float* __restrict__ dwT,
    float* __restrict__ Bx)
{
    int bx = blockIdx.x;
    if (bx < 288) {
        int idx8 = (bx * 256 + threadIdx.x) * 8;
        int which = idx8 / WMAT;
        int loc = idx8 - which * WMAT;
        const float* s = (which == 0) ? qp : (which == 1) ? kp : (which == 2) ? vp : pj;
        float4 v0 = *(const float4*)(s + loc);
        float4 v1 = *(const float4*)(s + loc + 4);
        us8 ov;
        ov[0] = f2bf(v0.x); ov[1] = f2bf(v0.y); ov[2] = f2bf(v0.z); ov[3] = f2bf(v0.w);
        ov[4] = f2bf(v1.x); ov[5] = f2bf(v1.y); ov[6] = f2bf(v1.z); ov[7] = f2bf(v1.w);
        *(us8*)(Wb + idx8) = ov;
    } else if (bx < 329) {
        int idx = (bx - 288) * 256 + threadIdx.x;
        if (idx < 3 * 9 * CCH) {
            int ten = idx / (9 * CCH);
            int rem = idx - ten * (9 * CCH);
            int tap = rem / CCH;
            int c   = rem - tap * CCH;
            const float* s = (ten == 0) ? qd : (ten == 1) ? kd : vd;
            dwT[idx] = s[c * 9 + tap];
        }
    } else {
        int idx = (bx - 329) * 256 + threadIdx.x;   // 192*256 = 49152 exact
        int h    = idx >> 12;
        int rem  = idx & 4095;
        int li   = rem >> 8;
        int rem2 = rem & 255;
        int g    = rem2 >> 6;
        int rem3 = rem2 & 63;
        int nf   = rem3 >> 4;
        int rem4 = rem3 & 15;
        int mf   = rem4 >> 2;
        int r    = rem4 & 3;
        int tk = nf * 16 + li;
        int tq = mf * 16 + g * 4 + r;
        int dy = (tq >> 3) - (tk >> 3) + 7;
        int dx = (tq & 7) - (tk & 7) + 7;
        Bx[idx] = rpb[(dy * 15 + dx) * HEADS + h];
    }
}

// ---------------------------------------------------------------------------
// FUSED depthwise 3x3 + bias + window-gather transpose (v7, proven 124us
// across 9 variants; structural latency floor at this block granularity).
// ---------------------------------------------------------------------------
__global__ __launch_bounds__(256) void dwgather(
    const float* __restrict__ x,
    const float* __restrict__ wt,       // [3][9][384] fp32 transposed dw weights
    const float* __restrict__ qb, const float* __restrict__ kb,
    const float* __restrict__ vb,
    unsigned short* __restrict__ oq, unsigned short* __restrict__ ok,
    unsigned short* __restrict__ ov)
{
    __shared__ float halo[64 * 121];        // 30.25 KB

    // bijective XCD swizzle: 6912 = 8 * 864
    int bid = blockIdx.x;
    int b = (bid & 7) * 864 + (bid >> 3);
    int wtx  = b % 24;
    int strip = b / 24;                     // 0..287
    int chv  = strip % 6;
    int nwy  = strip / 6;                   // 0..47
    int wy   = nwy % 24;
    int n    = nwy / 24;

    int h0 = wy * 8, w0 = wtx * 8;
    int tid = threadIdx.x;
    int c   = tid & 63;                     // channel within chunk (lane-varying)
    int pxg = tid >> 6;                     // wave id: owns pixel rows 2pxg,2pxg+1
    int cg  = chv * 64 + c;
    int widx = n * WINS + wy * NWIN + wtx;

    const float* xbase = x + (size_t)n * CCH * HWP + (size_t)(chv * 64) * HWP;

    // ---- stage halo: 64ch x 10 rows x 12 cols (cols w0-2 .. w0+9) ----
    for (int j = tid; j < 1920; j += 256) {
        int seg = j % 3;
        int t   = j / 3;
        int rr  = t % 10;
        int cc  = t / 10;
        int hr  = h0 - 1 + rr;
        int cb  = w0 - 2 + seg * 4;
        float4 val = make_float4(0.f, 0.f, 0.f, 0.f);
        if (hr >= 0 && hr < HH) {
            const float* p = xbase + (size_t)cc * HWP + (size_t)hr * WWD;
            if (cb >= 0 && cb + 4 <= WWD) {
                val = *(const float4*)(p + cb);
            } else {
                if (cb + 0 >= 0 && cb + 0 < WWD) val.x = p[cb + 0];
                if (cb + 1 >= 0 && cb + 1 < WWD) val.y = p[cb + 1];
                if (cb + 2 >= 0 && cb + 2 < WWD) val.z = p[cb + 2];
                if (cb + 3 >= 0 && cb + 3 < WWD) val.w = p[cb + 3];
            }
        }
        int hb = cc * 121 + rr * 12 + seg * 4;
        halo[hb + 0] = val.x;
        halo[hb + 1] = val.y;
        halo[hb + 2] = val.z;
        halo[hb + 3] = val.w;
    }

    // ---- per-lane weights, coalesced ([tap][384] layout) ----
    float wq[9], wk[9], wv[9];
#pragma unroll
    for (int t = 0; t < 9; ++t) {
        wq[t] = wt[t * CCH + cg];
        wk[t] = wt[9 * CCH + t * CCH + cg];
        wv[t] = wt[18 * CCH + t * CCH + cg];
    }
    float bqv = qb[cg], bkv = kb[cg], bvv = vb[cg];

    __syncthreads();

    // ---- register sliding window: rows 2pxg..2pxg+3, cols 1..10 ----
    const int hbase = c * 121 + (2 * pxg) * 12;
    float r0[10], r1[10], r2[10];
#pragma unroll
    for (int cc = 0; cc < 10; ++cc) r0[cc] = halo[hbase + cc + 1];
#pragma unroll
    for (int cc = 0; cc < 10; ++cc) r1[cc] = halo[hbase + 12 + cc + 1];
#pragma unroll
    for (int cc = 0; cc < 10; ++cc) r2[cc] = halo[hbase + 24 + cc + 1];

    size_t ob0 = ((size_t)widx * 64 + pxg * 16) * CCH + cg;

    // pixel row 0: taps r0,r1,r2
#pragma unroll
    for (int pc = 0; pc < 8; ++pc) {
        float sq = 0.f, sk = 0.f, sv = 0.f;
#pragma unroll
        for (int dc = 0; dc < 3; ++dc) {
            float x0 = r0[pc + dc], x1 = r1[pc + dc], x2 = r2[pc + dc];
            sq = fmaf(x0, wq[dc], sq);     sk = fmaf(x0, wk[dc], sk);     sv = fmaf(x0, wv[dc], sv);
            sq = fmaf(x1, wq[3 + dc], sq); sk = fmaf(x1, wk[3 + dc], sk); sv = fmaf(x1, wv[3 + dc], sv);
            sq = fmaf(x2, wq[6 + dc], sq); sk = fmaf(x2, wk[6 + dc], sk); sv = fmaf(x2, wv[6 + dc], sv);
        }
        size_t o = ob0 + (size_t)pc * CCH;
        oq[o] = f2bf(sq + bqv);
        ok[o] = f2bf(sk + bkv);
        ov[o] = f2bf(sv + bvv);
    }

    // rotate: r0 <- row 2pxg+3
#pragma unroll
    for (int cc = 0; cc < 10; ++cc) r0[cc] = halo[hbase + 36 + cc + 1];

    // pixel row 1: taps r1,r2,r0
#pragma unroll
    for (int pc = 0; pc < 8; ++pc) {
        float sq = 0.f, sk = 0.f, sv = 0.f;
#pragma unroll
        for (int dc = 0; dc < 3; ++dc) {
            float x0 = r1[pc + dc], x1 = r2[pc + dc], x2 = r0[pc + dc];
            sq = fmaf(x0, wq[dc], sq);     sk = fmaf(x0, wk[dc], sk);     sv = fmaf(x0, wv[dc], sv);
            sq = fmaf(x1, wq[3 + dc], sq); sk = fmaf(x1, wk[3 + dc], sk); sv = fmaf(x1, wv[3 + dc], sv);
            sq = fmaf(x2, wq[6 + dc], sq); sk = fmaf(x2, wk[6 + dc], sk); sv = fmaf(x2, wv[6 + dc], sv);
        }
        size_t o = ob0 + (size_t)(8 + pc) * CCH;
        oq[o] = f2bf(sq + bqv);
        ok[o] = f2bf(sk + bkv);
        ov[o] = f2bf(sv + bvv);
    }
}

// issue macro shared by both GEMMs: one K-tile (4 gload16 per wave)
#define ISSUE_TILE(KT, BUF)                                                     \
    do {                                                                        \
        int k0_ = (KT) * 32;                                                    \
        gload16(Wg0 + k0_,                     &Wt[BUF][wid * 32][0]);          \
        gload16(Wg0 + (size_t)16 * CCH + k0_,  &Wt[BUF][wid * 32 + 16][0]);     \
        gload16(Yg0 + k0_,                     &Yt[BUF][wid * 32][0]);          \
        gload16(Yg0 + (size_t)16 * CCH + k0_,  &Yt[BUF][wid * 32 + 16][0]);     \
    } while (0)

// ---------------------------------------------------------------------------
// MERGED q/k/v bf16 MFMA GEMM, depth-2 counted-vmcnt pipeline (T4) with
// register-preloaded bias (exact vmcnt ledger). No setprio (GEMM-null, m190).
// ---------------------------------------------------------------------------
__global__ __launch_bounds__(256) void qkv_gemm(
    const unsigned short* __restrict__ tr0, const unsigned short* __restrict__ tr1,
    const unsigned short* __restrict__ tr2, const unsigned short* __restrict__ Wball,
    const float* __restrict__ qpb, const float* __restrict__ kpb,
    const float* __restrict__ vpb, float scale,
    unsigned short* __restrict__ qo, unsigned short* __restrict__ ko,
    unsigned short* __restrict__ vo)
{
    __shared__ __align__(16) char smem[49152];   // staging [3] bufs U epilogue T16
    typedef unsigned short (*tile3)[128][32];
    tile3 Wt = (tile3)smem;                      // [3][128][32]
    tile3 Yt = (tile3)(smem + 24576);
    typedef unsigned short (*tep_t)[132];
    tep_t T16 = (tep_t)smem;

    // decode: O = tensor-major, then p-tile, c-tile innermost (L2 reuse of Y)
    int bL = blockIdx.x;
    int O  = (bL & 7) * 648 + (bL >> 3);
    int z  = O / 1728;
    int rem = O - z * 1728;
    int py = rem / 3;
    int cx = rem - py * 3;
    int pp0 = py * 128, cm0 = cx * 128;

    const unsigned short* Y  = (z == 0) ? tr0 : (z == 1) ? tr1 : tr2;
    const unsigned short* Wb = Wball + (size_t)z * WMAT;
    const float* bias        = (z == 0) ? qpb : (z == 1) ? kpb : vpb;
    float sc                 = (z == 0) ? scale : 1.0f;
    unsigned short* outb     = (z == 0) ? qo : (z == 1) ? ko : vo;
    bool vmode = (z == 2);

    int tid = threadIdx.x;
    int lid = tid & 63, wid = tid >> 6;
    int wr = wid >> 1, wc = wid & 1;
    int li = lid & 15, g = lid >> 4;

    // staging: srow 0..15 in 16-row group; SOURCE slot pre-swizzled
    int srow = (lid >> 2);
    int scol = (((lid & 3) ^ ((srow >> 1) & 3))) * 8;
    // read-side swizzled k-slot (row base multiples of 16 -> depends on li only)
    int gsw = (g ^ ((li >> 1) & 3)) * 8;

    fx4 acc[4][4];
#pragma unroll
    for (int i = 0; i < 4; ++i)
#pragma unroll
        for (int j = 0; j < 4; ++j) acc[i][j] = (fx4){0.f, 0.f, 0.f, 0.f};

    tile3 A3 = vmode ? Yt : Wt;          // block-uniform select
    tile3 B3 = vmode ? Wt : Yt;

    const unsigned short* Wg0 = Wb + (size_t)(cm0 + wid * 32 + srow) * CCH + scol;
    const unsigned short* Yg0 = Y  + (size_t)(pp0 + wid * 32 + srow) * CCH + scol;

    // ---- preload epilogue bias to registers, DRAIN, so loop vmcnt is exact --
    float4 bv4[4];
    float  bvs[4];
    if (!vmode) {
#pragma unroll
        for (int mf = 0; mf < 4; ++mf)
            bv4[mf] = *(const float4*)&bias[cm0 + wr * 64 + mf * 16 + g * 4];
    } else {
#pragma unroll
        for (int nf = 0; nf < 4; ++nf)
            bvs[nf] = bias[cm0 + wc * 64 + nf * 16 + li];
    }
    asm volatile("s_waitcnt vmcnt(0)" ::: "memory");
    __builtin_amdgcn_sched_barrier(0);

    ISSUE_TILE(0, 0);
    ISSUE_TILE(1, 1);

#pragma unroll
    for (int kt = 0; kt < 12; ++kt) {
        __builtin_amdgcn_sched_barrier(0);
        if (kt < 11) asm volatile("s_waitcnt vmcnt(4)" ::: "memory");
        else         asm volatile("s_waitcnt vmcnt(0)" ::: "memory");
        __builtin_amdgcn_s_barrier();            // raw: no implicit drain
        __builtin_amdgcn_sched_barrier(0);
        if (kt < 10) ISSUE_TILE(kt + 2, (kt + 2) % 3);

        int cur = kt % 3;
        bh8 a[4], b[4];
#pragma unroll
        for (int mf = 0; mf < 4; ++mf)
            a[mf] = *(const bh8*)&A3[cur][wr * 64 + mf * 16 + li][gsw];
#pragma unroll
        for (int nf = 0; nf < 4; ++nf)
            b[nf] = *(const bh8*)&B3[cur][wc * 64 + nf * 16 + li][gsw];
#pragma unroll
        for (int mf = 0; mf < 4; ++mf)
#pragma unroll
            for (int nf = 0; nf < 4; ++nf)
                acc[mf][nf] = __builtin_amdgcn_mfma_f32_16x16x32_bf16(
                    a[mf], b[nf], acc[mf][nf], 0, 0, 0);
    }

    __syncthreads();                     // staging dead; safe to overwrite w/ T16

    if (!vmode) {
        // D rows = c (A=W), cols = p. T16[p_local][c_local]; out [p][c].
#pragma unroll
        for (int mf = 0; mf < 4; ++mf) {
            int cl = wr * 64 + mf * 16 + g * 4;
            float4 bv = bv4[mf];
#pragma unroll
            for (int nf = 0; nf < 4; ++nf) {
                int pl = wc * 64 + nf * 16 + li;
                us4 o;
                o[0] = f2bf((acc[mf][nf][0] + bv.x) * sc);
                o[1] = f2bf((acc[mf][nf][1] + bv.y) * sc);
                o[2] = f2bf((acc[mf][nf][2] + bv.z) * sc);
                o[3] = f2bf((acc[mf][nf][3] + bv.w) * sc);
                *(us4*)&T16[pl][cl] = o;
            }
        }
        __syncthreads();
#pragma unroll
        for (int it = 0; it < 8; ++it) {
            int row = it * 16 + wid * 4 + (lid >> 4);
            int col = (lid & 15) * 8;
            us8 vv = *(const us8*)&T16[row][col];
            *(us8*)(outb + (size_t)(pp0 + row) * CCH + cm0 + col) = vv;
        }
    } else {
        // D rows = p (A=Y), cols = c. T16[c_local][p_local]; out [n][c][p_l].
#pragma unroll
        for (int nf = 0; nf < 4; ++nf) {
            int cl = wc * 64 + nf * 16 + li;
            float bv = bvs[nf];
#pragma unroll
            for (int mf = 0; mf < 4; ++mf) {
                int pl = wr * 64 + mf * 16 + g * 4;
                us4 o;
                o[0] = f2bf(acc[mf][nf][0] + bv);
                o[1] = f2bf(acc[mf][nf][1] + bv);
                o[2] = f2bf(acc[mf][nf][2] + bv);
                o[3] = f2bf(acc[mf][nf][3] + bv);
                *(us4*)&T16[cl][pl] = o;
            }
        }
        __syncthreads();
        int n = pp0 / HWP;
        int pl0 = pp0 - n * HWP;
#pragma unroll
        for (int it = 0; it < 8; ++it) {
            int row = it * 16 + wid * 4 + (lid >> 4);   // c_local
            int col = (lid & 15) * 8;                   // p_local
            us8 vv = *(const us8*)&T16[row][col];
            *(us8*)(outb + (size_t)(n * CCH + cm0 + row) * HWP + pl0 + col) = vv;
        }
    }
}

// ---------------------------------------------------------------------------
// proj GEMM: depth-2 counted-vmcnt pipeline with preloaded+drained bias;
// direct fp32 scatter stores. 1-D grid 1728 = 8 x 216, c-tile innermost.
// ---------------------------------------------------------------------------
__global__ __launch_bounds__(256) void proj_gemm(
    const unsigned short* __restrict__ Y, const unsigned short* __restrict__ Wb,
    const float* __restrict__ bias, float* __restrict__ outf)
{
    __shared__ unsigned short Wt[3][128][32];
    __shared__ unsigned short Yt[3][128][32];

    int bL = blockIdx.x;
    int O  = (bL & 7) * 216 + (bL >> 3);
    int py = O / 3;
    int cx = O - py * 3;
    int pp0 = py * 128, cm0 = cx * 128;

    int tid = threadIdx.x;
    int lid = tid & 63, wid = tid >> 6;
    int wr = wid >> 1, wc = wid & 1;
    int li = lid & 15, g = lid >> 4;

    int srow = (lid >> 2);
    int scol = (((lid & 3) ^ ((srow >> 1) & 3))) * 8;
    int gsw = (g ^ ((li >> 1) & 3)) * 8;

    fx4 acc[4][4];
#pragma unroll
    for (int i = 0; i < 4; ++i)
#pragma unroll
        for (int j = 0; j < 4; ++j) acc[i][j] = (fx4){0.f, 0.f, 0.f, 0.f};

    const unsigned short* Wg0 = Wb + (size_t)(cm0 + wid * 32 + srow) * CCH + scol;
    const unsigned short* Yg0 = Y  + (size_t)(pp0 + wid * 32 + srow) * CCH + scol;

    // preload bias (float4 per mf), drain so loop vmcnt ledger is exact
    float4 bv4[4];
#pragma unroll
    for (int mf = 0; mf < 4; ++mf)
        bv4[mf] = *(const float4*)&bias[cm0 + wr * 64 + mf * 16 + g * 4];
    asm volatile("s_waitcnt vmcnt(0)" ::: "memory");
    __builtin_amdgcn_sched_barrier(0);

    ISSUE_TILE(0, 0);
    ISSUE_TILE(1, 1);

#pragma unroll
    for (int kt = 0; kt < 12; ++kt) {
        __builtin_amdgcn_sched_barrier(0);
        if (kt < 11) asm volatile("s_waitcnt vmcnt(4)" ::: "memory");
        else         asm volatile("s_waitcnt vmcnt(0)" ::: "memory");
        __builtin_amdgcn_s_barrier();
        __builtin_amdgcn_sched_barrier(0);
        if (kt < 10) ISSUE_TILE(kt + 2, (kt + 2) % 3);

        int cur = kt % 3;
        bh8 a[4], b[4];
#pragma unroll
        for (int mf = 0; mf < 4; ++mf)
            a[mf] = *(const bh8*)&Wt[cur][wr * 64 + mf * 16 + li][gsw];
#pragma unroll
        for (int nf = 0; nf < 4; ++nf)
            b[nf] = *(const bh8*)&Yt[cur][wc * 64 + nf * 16 + li][gsw];
#pragma unroll
        for (int mf = 0; mf < 4; ++mf)
#pragma unroll
            for (int nf = 0; nf < 4; ++nf)
                acc[mf][nf] = __builtin_amdgcn_mfma_f32_16x16x32_bf16(
                    a[mf], b[nf], acc[mf][nf], 0, 0, 0);
    }

    // D rows = c, cols = p (lane). fp32 std layout, un-gather windows.
#pragma unroll
    for (int mf = 0; mf < 4; ++mf) {
        int c = cm0 + wr * 64 + mf * 16 + g * 4;
#pragma unroll
        for (int nf = 0; nf < 4; ++nf) {
            int p = pp0 + wc * 64 + nf * 16 + li;
            int n = p / HWP;
            int rem = p - n * HWP;
            int win = rem >> 6, t = rem & 63;
            int h = (win / NWIN) * 8 + (t >> 3);
            int w = (win % NWIN) * 8 + (t & 7);
            float* op = outf + (size_t)n * CCH * HWP + (size_t)h * WWD + w;
            op[(size_t)(c + 0) * HWP] = acc[mf][nf][0] + bv4[mf].x;
            op[(size_t)(c + 1) * HWP] = acc[mf][nf][1] + bv4[mf].y;
            op[(size_t)(c + 2) * HWP] = acc[mf][nf][2] + bv4[mf].z;
            op[(size_t)(c + 3) * HWP] = acc[mf][nf][3] + bv4[mf].w;
        }
    }
}

// ---------------------------------------------------------------------------
// MFMA window attention v3: wave = ONE (window, head) pair; grid 3456 = 8x432.
// Bx lane-coalesced [h][li][g][nf][mf][4]; Pl halved [4][64][36].
// ---------------------------------------------------------------------------
__global__ __launch_bounds__(256) void attn(
    const unsigned short* __restrict__ q, const unsigned short* __restrict__ k,
    const unsigned short* __restrict__ v, const float* __restrict__ Bx,
    unsigned short* __restrict__ o)
{
    __shared__ unsigned short Pl[4][64][36];

    int tid = threadIdx.x, lid = tid & 63, wid = tid >> 6;
    int bL = blockIdx.x;
    int b = (bL & 7) * 432 + (bL >> 3);     // bijective XCD swizzle
    int pair = b * 4 + wid;                 // 0..13823
    int wl = pair / 12;
    int hq = pair - wl * 12;
    int n = wl / WINS, winl = wl - n * WINS;
    int li = lid & 15, g = lid >> 4;

    const fx4 z = (fx4){0.f, 0.f, 0.f, 0.f};

    const unsigned short* qp = q + (size_t)(wl * 64) * CCH + hq * HD + g * 8;
    const unsigned short* kp = k + (size_t)(wl * 64) * CCH + hq * HD + g * 8;
    bh8 aq[4], bk[4];
#pragma unroll
    for (int mf = 0; mf < 4; ++mf)
        aq[mf] = *(const bh8*)(qp + (size_t)(mf * 16 + li) * CCH);
#pragma unroll
    for (int nf = 0; nf < 4; ++nf)
        bk[nf] = *(const bh8*)(kp + (size_t)(nf * 16 + li) * CCH);

    // hoisted V loads (independent): softmax covers their latency
    bh8 av2[2][2];
#pragma unroll
    for (int ks = 0; ks < 2; ++ks)
#pragma unroll
        for (int m2 = 0; m2 < 2; ++m2)
            av2[ks][m2] = *(const bh8*)(v + (size_t)(n * CCH + hq * HD + m2 * 16 + li) * HWP
                                          + winl * 64 + ks * 32 + g * 8);

    fx4 s[4][4];
    __builtin_amdgcn_s_setprio(1);
#pragma unroll
    for (int mf = 0; mf < 4; ++mf)
#pragma unroll
        for (int nf = 0; nf < 4; ++nf)
            s[mf][nf] = __builtin_amdgcn_mfma_f32_16x16x32_bf16(aq[mf], bk[nf], z, 0, 0, 0);
    __builtin_amdgcn_s_setprio(0);

    // bias: lane-coalesced table, per-lane contiguous 256 B
    {
        const float* bxl = Bx + (((size_t)hq * 16 + li) * 4 + g) * 64;
#pragma unroll
        for (int nf = 0; nf < 4; ++nf)
#pragma unroll
            for (int mf = 0; mf < 4; ++mf) {
                fx4 bv = *(const fx4*)&bxl[(nf * 4 + mf) * 4];
                s[mf][nf] += bv;
            }
    }

    // softmax across tk (lane group of 16 shares a row set)
    float inv_[4][4];
#pragma unroll
    for (int mf = 0; mf < 4; ++mf)
#pragma unroll
        for (int r = 0; r < 4; ++r) {
            float m = s[mf][0][r];
#pragma unroll
            for (int nf = 1; nf < 4; ++nf) m = fmaxf(m, s[mf][nf][r]);
            m = fmaxf(m, __shfl_xor(m, 1));
            m = fmaxf(m, __shfl_xor(m, 2));
            m = fmaxf(m, __shfl_xor(m, 4));
            m = fmaxf(m, __shfl_xor(m, 8));
            float sum = 0.f;
#pragma unroll
            for (int nf = 0; nf < 4; ++nf) {
                float e = __expf(s[mf][nf][r] - m);
                s[mf][nf][r] = e;
                sum += e;
            }
            sum += __shfl_xor(sum, 1);
            sum += __shfl_xor(sum, 2);
            sum += __shfl_xor(sum, 4);
            sum += __shfl_xor(sum, 8);
            inv_[mf][r] = 1.f / sum;
        }

    // O^T = V^T x P^T : D[d][tq], P processed per tk-half through halved Pl
    fx4 o2[2][4];
#pragma unroll
    for (int m2 = 0; m2 < 2; ++m2)
#pragma unroll
        for (int nf = 0; nf < 4; ++nf) o2[m2][nf] = z;

#pragma unroll
    for (int ks = 0; ks < 2; ++ks) {
        // write this tk-half of P (tk = ks*32 + nf2*16 + li)
#pragma unroll
        for (int mf = 0; mf < 4; ++mf)
#pragma unroll
            for (int nf2 = 0; nf2 < 2; ++nf2) {
                int nf = ks * 2 + nf2;
#pragma unroll
                for (int r = 0; r < 4; ++r)
                    Pl[wid][mf * 16 + g * 4 + r][nf2 * 16 + li] =
                        f2bf(s[mf][nf][r] * inv_[mf][r]);
            }
        // read B-fragments (tq-block nfq, k-slice within half) and accumulate
        bh8 bp[4];
#pragma unroll
        for (int nfq = 0; nfq < 4; ++nfq)
            bp[nfq] = *(const bh8*)&Pl[wid][nfq * 16 + li][g * 8];
        __builtin_amdgcn_s_setprio(1);
#pragma unroll
        for (int m2 = 0; m2 < 2; ++m2)
#pragma unroll
            for (int nfq = 0; nfq < 4; ++nfq)
                o2[m2][nfq] = __builtin_amdgcn_mfma_f32_16x16x32_bf16(
                    av2[ks][m2], bp[nfq], o2[m2][nfq], 0, 0, 0);
        __builtin_amdgcn_s_setprio(0);
    }

#pragma unroll
    for (int nf = 0; nf < 4; ++nf) {
        int tq = nf * 16 + li;
#pragma unroll
        for (int m2 = 0; m2 < 2; ++m2) {
            int d = hq * HD + m2 * 16 + g * 4;
            us4 ov;
            ov[0] = f2bf(o2[m2][nf][0]);
            ov[1] = f2bf(o2[m2][nf][1]);
            ov[2] = f2bf(o2[m2][nf][2]);
            ov[3] = f2bf(o2[m2][nf][3]);
            *(us4*)(o + (size_t)(wl * 64 + tq) * CCH + d) = ov;
        }
    }
}

// ---------------------------------------------------------------------------
extern "C" void kernel_launch(void* const* d_in, const int* in_sizes, int n_in,
                              void* d_out, int out_size, void* d_ws, size_t ws_size,
                              hipStream_t stream) {
    const float* vid  = (const float*)d_in[0];
    const float* qd_w = (const float*)d_in[1];
    const float* qd_b = (const float*)d_in[2];
    const float* qp_w = (const float*)d_in[3];
    const float* qp_b = (const float*)d_in[4];
    const float* kd_w = (const float*)d_in[5];
    const float* kd_b = (const float*)d_in[6];
    const float* kp_w = (const float*)d_in[7];
    const float* kp_b = (const float*)d_in[8];
    const float* vd_w = (const float*)d_in[9];
    const float* vd_b = (const float*)d_in[10];
    const float* vp_w = (const float*)d_in[11];
    const float* vp_b = (const float*)d_in[12];
    const float* rpb  = (const float*)d_in[13];
    const float* pj_w = (const float*)d_in[14];
    const float* pj_b = (const float*)d_in[15];

    unsigned short* ws16 = (unsigned short*)d_ws;
    unsigned short* tr0 = ws16 + 3 * EELEM;     // [p_wg][c] bf16 (q,k,v pre-GEMM)
    unsigned short* tr1 = ws16 + 4 * EELEM;
    unsigned short* tr2 = ws16 + 5 * EELEM;
    unsigned short* Wb  = ws16 + 6 * EELEM;     // 4 x 147456 bf16
    float* dwT          = (float*)(Wb + 4 * WMAT);      // [3][9][384] fp32
    float* Bx           = dwT + 3 * 9 * CCH;            // [12][16][4][4][4][4] fp32
    unsigned short* qb  = ws16;                 // post-GEMM q,k,v
    unsigned short* kb  = ws16 + EELEM;
    unsigned short* vb  = ws16 + 2 * EELEM;
    unsigned short* ob  = tr0;                  // attn out reuses tr region

    prep<<<521, 256, 0, stream>>>(qp_w, kp_w, vp_w, pj_w,
                                  qd_w, kd_w, vd_w, rpb, Wb, dwT, Bx);
    dwgather<<<NIMG * WINS * 6, 256, 0, stream>>>(
        vid, dwT, qd_b, kd_b, vd_b, tr0, tr1, tr2);

    const float scale = 0.17677669529663687f;   // 32^-0.5 folded into q
    qkv_gemm<<<5184, 256, 0, stream>>>(
        tr0, tr1, tr2, Wb, qp_b, kp_b, vp_b, scale, qb, kb, vb);

    attn<<<3456, 256, 0, stream>>>(qb, kb, vb, Bx, ob);

    proj_gemm<<<1728, 256, 0, stream>>>(
        ob, Wb + 3 * WMAT, pj_b, (float*)d_out);
}

// Round 20
// 353.227 us; speedup vs baseline: 1.1569x; 1.0813x over previous
//
#include <hip/hip_runtime.h>

#define CCH 384
#define HH 192
#define WWD 192
#define NIMG 2
#define HWP (HH * WWD)        // 36864 pixels per image
#define PTOT (NIMG * HWP)     // 73728
#define HEADS 12
#define HD 32
#define NWIN 24
#define WINS 576              // windows per image
#define EELEM ((size_t)NIMG * CCH * HWP)   // elems per tensor (28,311,552)
#define WMAT 147456           // 384*384

typedef __attribute__((ext_vector_type(8))) short bh8;            // 8 bf16 (MFMA frag)
typedef __attribute__((ext_vector_type(8))) unsigned short us8;
typedef __attribute__((ext_vector_type(4))) unsigned short us4;
typedef __attribute__((ext_vector_type(4))) float fx4;

__device__ __forceinline__ unsigned short f2bf(float f) {
    unsigned u = __float_as_uint(f);
    u += 0x7fffu + ((u >> 16) & 1u);      // round-to-nearest-even
    return (unsigned short)(u >> 16);
}

__device__ __forceinline__ void gload16(const void* g, void* l) {
    __builtin_amdgcn_global_load_lds(
        (const __attribute__((address_space(1))) void*)g,
        (__attribute__((address_space(3))) void*)l, 16, 0, 0);
}

// ---------------------------------------------------------------------------
// prep (merged): [0,288) pw weights->bf16; [288,329) dw weight transpose;
// [329,521) rel-pos bias expansion, LANE-COALESCED layout:
//   Bx[h][li][g][nf][mf][r]  (per attn-lane contiguous 256 B run)
// ---------------------------------------------------------------------------
__global__ __launch_bounds__(256) void prep(
    const float* __restrict__ qp, const float* __restrict__ kp,
    const float* __restrict__ vp, const float* __restrict__ pj,
    const float* __restrict__ qd, const float* __restrict__ kd,
    const float* __restrict__ vd, const float* __restrict__ rpb,
    unsigned short* __restrict__ Wb, float* __restrict__ dwT,
    float* __restrict__ Bx)
{
    int bx = blockIdx.x;
    if (bx < 288) {
        int idx8 = (bx * 256 + threadIdx.x) * 8;
        int which = idx8 / WMAT;
        int loc = idx8 - which * WMAT;
        const float* s = (which == 0) ? qp : (which == 1) ? kp : (which == 2) ? vp : pj;
        float4 v0 = *(const float4*)(s + loc);
        float4 v1 = *(const float4*)(s + loc + 4);
        us8 ov;
        ov[0] = f2bf(v0.x); ov[1] = f2bf(v0.y); ov[2] = f2bf(v0.z); ov[3] = f2bf(v0.w);
        ov[4] = f2bf(v1.x); ov[5] = f2bf(v1.y); ov[6] = f2bf(v1.z); ov[7] = f2bf(v1.w);
        *(us8*)(Wb + idx8) = ov;
    } else if (bx < 329) {
        int idx = (bx - 288) * 256 + threadIdx.x;
        if (idx < 3 * 9 * CCH) {
            int ten = idx / (9 * CCH);
            int rem = idx - ten * (9 * CCH);
            int tap = rem / CCH;
            int c   = rem - tap * CCH;
            const float* s = (ten == 0) ? qd : (ten == 1) ? kd : vd;
            dwT[idx] = s[c * 9 + tap];
        }
    } else {
        int idx = (bx - 329) * 256 + threadIdx.x;   // 192*256 = 49152 exact
        int h    = idx >> 12;
        int rem  = idx & 4095;
        int li   = rem >> 8;
        int rem2 = rem & 255;
        int g    = rem2 >> 6;
        int rem3 = rem2 & 63;
        int nf   = rem3 >> 4;
        int rem4 = rem3 & 15;
        int mf   = rem4 >> 2;
        int r    = rem4 & 3;
        int tk = nf * 16 + li;
        int tq = mf * 16 + g * 4 + r;
        int dy = (tq >> 3) - (tk >> 3) + 7;
        int dx = (tq & 7) - (tk & 7) + 7;
        Bx[idx] = rpb[(dy * 15 + dx) * HEADS + h];
    }
}

// ---------------------------------------------------------------------------
// FUSED depthwise 3x3 + bias + window-gather transpose (v7, proven 124us).
// ---------------------------------------------------------------------------
__global__ __launch_bounds__(256) void dwgather(
    const float* __restrict__ x,
    const float* __restrict__ wt,       // [3][9][384] fp32 transposed dw weights
    const float* __restrict__ qb, const float* __restrict__ kb,
    const float* __restrict__ vb,
    unsigned short* __restrict__ oq, unsigned short* __restrict__ ok,
    unsigned short* __restrict__ ov)
{
    __shared__ float halo[64 * 121];        // 30.25 KB

    // bijective XCD swizzle: 6912 = 8 * 864
    int bid = blockIdx.x;
    int b = (bid & 7) * 864 + (bid >> 3);
    int wtx  = b % 24;
    int strip = b / 24;                     // 0..287
    int chv  = strip % 6;
    int nwy  = strip / 6;                   // 0..47
    int wy   = nwy % 24;
    int n    = nwy / 24;

    int h0 = wy * 8, w0 = wtx * 8;
    int tid = threadIdx.x;
    int c   = tid & 63;                     // channel within chunk (lane-varying)
    int pxg = tid >> 6;                     // wave id: owns pixel rows 2pxg,2pxg+1
    int cg  = chv * 64 + c;
    int widx = n * WINS + wy * NWIN + wtx;

    const float* xbase = x + (size_t)n * CCH * HWP + (size_t)(chv * 64) * HWP;

    // ---- stage halo: 64ch x 10 rows x 12 cols (cols w0-2 .. w0+9) ----
    for (int j = tid; j < 1920; j += 256) {
        int seg = j % 3;
        int t   = j / 3;
        int rr  = t % 10;
        int cc  = t / 10;
        int hr  = h0 - 1 + rr;
        int cb  = w0 - 2 + seg * 4;
        float4 val = make_float4(0.f, 0.f, 0.f, 0.f);
        if (hr >= 0 && hr < HH) {
            const float* p = xbase + (size_t)cc * HWP + (size_t)hr * WWD;
            if (cb >= 0 && cb + 4 <= WWD) {
                val = *(const float4*)(p + cb);
            } else {
                if (cb + 0 >= 0 && cb + 0 < WWD) val.x = p[cb + 0];
                if (cb + 1 >= 0 && cb + 1 < WWD) val.y = p[cb + 1];
                if (cb + 2 >= 0 && cb + 2 < WWD) val.z = p[cb + 2];
                if (cb + 3 >= 0 && cb + 3 < WWD) val.w = p[cb + 3];
            }
        }
        int hb = cc * 121 + rr * 12 + seg * 4;
        halo[hb + 0] = val.x;
        halo[hb + 1] = val.y;
        halo[hb + 2] = val.z;
        halo[hb + 3] = val.w;
    }

    // ---- per-lane weights, coalesced ([tap][384] layout) ----
    float wq[9], wk[9], wv[9];
#pragma unroll
    for (int t = 0; t < 9; ++t) {
        wq[t] = wt[t * CCH + cg];
        wk[t] = wt[9 * CCH + t * CCH + cg];
        wv[t] = wt[18 * CCH + t * CCH + cg];
    }
    float bqv = qb[cg], bkv = kb[cg], bvv = vb[cg];

    __syncthreads();

    // ---- register sliding window: rows 2pxg..2pxg+3, cols 1..10 ----
    const int hbase = c * 121 + (2 * pxg) * 12;
    float r0[10], r1[10], r2[10];
#pragma unroll
    for (int cc = 0; cc < 10; ++cc) r0[cc] = halo[hbase + cc + 1];
#pragma unroll
    for (int cc = 0; cc < 10; ++cc) r1[cc] = halo[hbase + 12 + cc + 1];
#pragma unroll
    for (int cc = 0; cc < 10; ++cc) r2[cc] = halo[hbase + 24 + cc + 1];

    size_t ob0 = ((size_t)widx * 64 + pxg * 16) * CCH + cg;

    // pixel row 0: taps r0,r1,r2
#pragma unroll
    for (int pc = 0; pc < 8; ++pc) {
        float sq = 0.f, sk = 0.f, sv = 0.f;
#pragma unroll
        for (int dc = 0; dc < 3; ++dc) {
            float x0 = r0[pc + dc], x1 = r1[pc + dc], x2 = r2[pc + dc];
            sq = fmaf(x0, wq[dc], sq);     sk = fmaf(x0, wk[dc], sk);     sv = fmaf(x0, wv[dc], sv);
            sq = fmaf(x1, wq[3 + dc], sq); sk = fmaf(x1, wk[3 + dc], sk); sv = fmaf(x1, wv[3 + dc], sv);
            sq = fmaf(x2, wq[6 + dc], sq); sk = fmaf(x2, wk[6 + dc], sk); sv = fmaf(x2, wv[6 + dc], sv);
        }
        size_t o = ob0 + (size_t)pc * CCH;
        oq[o] = f2bf(sq + bqv);
        ok[o] = f2bf(sk + bkv);
        ov[o] = f2bf(sv + bvv);
    }

    // rotate: r0 <- row 2pxg+3
#pragma unroll
    for (int cc = 0; cc < 10; ++cc) r0[cc] = halo[hbase + 36 + cc + 1];

    // pixel row 1: taps r1,r2,r0
#pragma unroll
    for (int pc = 0; pc < 8; ++pc) {
        float sq = 0.f, sk = 0.f, sv = 0.f;
#pragma unroll
        for (int dc = 0; dc < 3; ++dc) {
            float x0 = r1[pc + dc], x1 = r2[pc + dc], x2 = r0[pc + dc];
            sq = fmaf(x0, wq[dc], sq);     sk = fmaf(x0, wk[dc], sk);     sv = fmaf(x0, wv[dc], sv);
            sq = fmaf(x1, wq[3 + dc], sq); sk = fmaf(x1, wk[3 + dc], sk); sv = fmaf(x1, wv[3 + dc], sv);
            sq = fmaf(x2, wq[6 + dc], sq); sk = fmaf(x2, wk[6 + dc], sk); sv = fmaf(x2, wv[6 + dc], sv);
        }
        size_t o = ob0 + (size_t)(8 + pc) * CCH;
        oq[o] = f2bf(sq + bqv);
        ok[o] = f2bf(sk + bkv);
        ov[o] = f2bf(sv + bvv);
    }
}

// issue macro shared by both GEMMs: one K-tile (4 gload16 per wave)
#define ISSUE_TILE(KT, BUF)                                                     \
    do {                                                                        \
        int k0_ = (KT) * 32;                                                    \
        gload16(Wg0 + k0_,                     &Wt[BUF][wid * 32][0]);          \
        gload16(Wg0 + (size_t)16 * CCH + k0_,  &Wt[BUF][wid * 32 + 16][0]);     \
        gload16(Yg0 + k0_,                     &Yt[BUF][wid * 32][0]);          \
        gload16(Yg0 + (size_t)16 * CCH + k0_,  &Yt[BUF][wid * 32 + 16][0]);     \
    } while (0)

// ---------------------------------------------------------------------------
// MERGED q/k/v bf16 MFMA GEMM, depth-2 counted-vmcnt pipeline (T4) with
// register-preloaded bias (exact vmcnt ledger). No setprio (GEMM-null, m190).
// ---------------------------------------------------------------------------
__global__ __launch_bounds__(256) void qkv_gemm(
    const unsigned short* __restrict__ tr0, const unsigned short* __restrict__ tr1,
    const unsigned short* __restrict__ tr2, const unsigned short* __restrict__ Wball,
    const float* __restrict__ qpb, const float* __restrict__ kpb,
    const float* __restrict__ vpb, float scale,
    unsigned short* __restrict__ qo, unsigned short* __restrict__ ko,
    unsigned short* __restrict__ vo)
{
    __shared__ __align__(16) char smem[49152];   // staging [3] bufs U epilogue T16
    typedef unsigned short (*tile3)[128][32];
    tile3 Wt = (tile3)smem;                      // [3][128][32]
    tile3 Yt = (tile3)(smem + 24576);
    typedef unsigned short (*tep_t)[132];
    tep_t T16 = (tep_t)smem;

    // decode: O = tensor-major, then p-tile, c-tile innermost (L2 reuse of Y)
    int bL = blockIdx.x;
    int O  = (bL & 7) * 648 + (bL >> 3);
    int z  = O / 1728;
    int rem = O - z * 1728;
    int py = rem / 3;
    int cx = rem - py * 3;
    int pp0 = py * 128, cm0 = cx * 128;

    const unsigned short* Y  = (z == 0) ? tr0 : (z == 1) ? tr1 : tr2;
    const unsigned short* Wb = Wball + (size_t)z * WMAT;
    const float* bias        = (z == 0) ? qpb : (z == 1) ? kpb : vpb;
    float sc                 = (z == 0) ? scale : 1.0f;
    unsigned short* outb     = (z == 0) ? qo : (z == 1) ? ko : vo;
    bool vmode = (z == 2);

    int tid = threadIdx.x;
    int lid = tid & 63, wid = tid >> 6;
    int wr = wid >> 1, wc = wid & 1;
    int li = lid & 15, g = lid >> 4;

    // staging: srow 0..15 in 16-row group; SOURCE slot pre-swizzled
    int srow = (lid >> 2);
    int scol = (((lid & 3) ^ ((srow >> 1) & 3))) * 8;
    // read-side swizzled k-slot (row base multiples of 16 -> depends on li only)
    int gsw = (g ^ ((li >> 1) & 3)) * 8;

    fx4 acc[4][4];
#pragma unroll
    for (int i = 0; i < 4; ++i)
#pragma unroll
        for (int j = 0; j < 4; ++j) acc[i][j] = (fx4){0.f, 0.f, 0.f, 0.f};

    tile3 A3 = vmode ? Yt : Wt;          // block-uniform select
    tile3 B3 = vmode ? Wt : Yt;

    const unsigned short* Wg0 = Wb + (size_t)(cm0 + wid * 32 + srow) * CCH + scol;
    const unsigned short* Yg0 = Y  + (size_t)(pp0 + wid * 32 + srow) * CCH + scol;

    // ---- preload epilogue bias to registers, DRAIN, so loop vmcnt is exact --
    float4 bv4[4];
    float  bvs[4];
    if (!vmode) {
#pragma unroll
        for (int mf = 0; mf < 4; ++mf)
            bv4[mf] = *(const float4*)&bias[cm0 + wr * 64 + mf * 16 + g * 4];
    } else {
#pragma unroll
        for (int nf = 0; nf < 4; ++nf)
            bvs[nf] = bias[cm0 + wc * 64 + nf * 16 + li];
    }
    asm volatile("s_waitcnt vmcnt(0)" ::: "memory");
    __builtin_amdgcn_sched_barrier(0);

    ISSUE_TILE(0, 0);
    ISSUE_TILE(1, 1);

#pragma unroll
    for (int kt = 0; kt < 12; ++kt) {
        __builtin_amdgcn_sched_barrier(0);
        if (kt < 11) asm volatile("s_waitcnt vmcnt(4)" ::: "memory");
        else         asm volatile("s_waitcnt vmcnt(0)" ::: "memory");
        __builtin_amdgcn_s_barrier();            // raw: no implicit drain
        __builtin_amdgcn_sched_barrier(0);
        if (kt < 10) ISSUE_TILE(kt + 2, (kt + 2) % 3);

        int cur = kt % 3;
        bh8 a[4], b[4];
#pragma unroll
        for (int mf = 0; mf < 4; ++mf)
            a[mf] = *(const bh8*)&A3[cur][wr * 64 + mf * 16 + li][gsw];
#pragma unroll
        for (int nf = 0; nf < 4; ++nf)
            b[nf] = *(const bh8*)&B3[cur][wc * 64 + nf * 16 + li][gsw];
#pragma unroll
        for (int mf = 0; mf < 4; ++mf)
#pragma unroll
            for (int nf = 0; nf < 4; ++nf)
                acc[mf][nf] = __builtin_amdgcn_mfma_f32_16x16x32_bf16(
                    a[mf], b[nf], acc[mf][nf], 0, 0, 0);
    }

    __syncthreads();                     // staging dead; safe to overwrite w/ T16

    if (!vmode) {
        // D rows = c (A=W), cols = p. T16[p_local][c_local]; out [p][c].
#pragma unroll
        for (int mf = 0; mf < 4; ++mf) {
            int cl = wr * 64 + mf * 16 + g * 4;
            float4 bv = bv4[mf];
#pragma unroll
            for (int nf = 0; nf < 4; ++nf) {
                int pl = wc * 64 + nf * 16 + li;
                us4 o;
                o[0] = f2bf((acc[mf][nf][0] + bv.x) * sc);
                o[1] = f2bf((acc[mf][nf][1] + bv.y) * sc);
                o[2] = f2bf((acc[mf][nf][2] + bv.z) * sc);
                o[3] = f2bf((acc[mf][nf][3] + bv.w) * sc);
                *(us4*)&T16[pl][cl] = o;
            }
        }
        __syncthreads();
#pragma unroll
        for (int it = 0; it < 8; ++it) {
            int row = it * 16 + wid * 4 + (lid >> 4);
            int col = (lid & 15) * 8;
            us8 vv = *(const us8*)&T16[row][col];
            *(us8*)(outb + (size_t)(pp0 + row) * CCH + cm0 + col) = vv;
        }
    } else {
        // D rows = p (A=Y), cols = c. T16[c_local][p_local]; out [n][c][p_l].
#pragma unroll
        for (int nf = 0; nf < 4; ++nf) {
            int cl = wc * 64 + nf * 16 + li;
            float bv = bvs[nf];
#pragma unroll
            for (int mf = 0; mf < 4; ++mf) {
                int pl = wr * 64 + mf * 16 + g * 4;
                us4 o;
                o[0] = f2bf(acc[mf][nf][0] + bv);
                o[1] = f2bf(acc[mf][nf][1] + bv);
                o[2] = f2bf(acc[mf][nf][2] + bv);
                o[3] = f2bf(acc[mf][nf][3] + bv);
                *(us4*)&T16[cl][pl] = o;
            }
        }
        __syncthreads();
        int n = pp0 / HWP;
        int pl0 = pp0 - n * HWP;
#pragma unroll
        for (int it = 0; it < 8; ++it) {
            int row = it * 16 + wid * 4 + (lid >> 4);   // c_local
            int col = (lid & 15) * 8;                   // p_local
            us8 vv = *(const us8*)&T16[row][col];
            *(us8*)(outb + (size_t)(n * CCH + cm0 + row) * HWP + pl0 + col) = vv;
        }
    }
}

// ---------------------------------------------------------------------------
// proj GEMM: depth-2 counted-vmcnt pipeline with preloaded+drained bias;
// direct fp32 scatter stores. 1-D grid 1728 = 8 x 216, c-tile innermost.
// ---------------------------------------------------------------------------
__global__ __launch_bounds__(256) void proj_gemm(
    const unsigned short* __restrict__ Y, const unsigned short* __restrict__ Wb,
    const float* __restrict__ bias, float* __restrict__ outf)
{
    __shared__ unsigned short Wt[3][128][32];
    __shared__ unsigned short Yt[3][128][32];

    int bL = blockIdx.x;
    int O  = (bL & 7) * 216 + (bL >> 3);
    int py = O / 3;
    int cx = O - py * 3;
    int pp0 = py * 128, cm0 = cx * 128;

    int tid = threadIdx.x;
    int lid = tid & 63, wid = tid >> 6;
    int wr = wid >> 1, wc = wid & 1;
    int li = lid & 15, g = lid >> 4;

    int srow = (lid >> 2);
    int scol = (((lid & 3) ^ ((srow >> 1) & 3))) * 8;
    int gsw = (g ^ ((li >> 1) & 3)) * 8;

    fx4 acc[4][4];
#pragma unroll
    for (int i = 0; i < 4; ++i)
#pragma unroll
        for (int j = 0; j < 4; ++j) acc[i][j] = (fx4){0.f, 0.f, 0.f, 0.f};

    const unsigned short* Wg0 = Wb + (size_t)(cm0 + wid * 32 + srow) * CCH + scol;
    const unsigned short* Yg0 = Y  + (size_t)(pp0 + wid * 32 + srow) * CCH + scol;

    // preload bias (float4 per mf), drain so loop vmcnt ledger is exact
    float4 bv4[4];
#pragma unroll
    for (int mf = 0; mf < 4; ++mf)
        bv4[mf] = *(const float4*)&bias[cm0 + wr * 64 + mf * 16 + g * 4];
    asm volatile("s_waitcnt vmcnt(0)" ::: "memory");
    __builtin_amdgcn_sched_barrier(0);

    ISSUE_TILE(0, 0);
    ISSUE_TILE(1, 1);

#pragma unroll
    for (int kt = 0; kt < 12; ++kt) {
        __builtin_amdgcn_sched_barrier(0);
        if (kt < 11) asm volatile("s_waitcnt vmcnt(4)" ::: "memory");
        else         asm volatile("s_waitcnt vmcnt(0)" ::: "memory");
        __builtin_amdgcn_s_barrier();
        __builtin_amdgcn_sched_barrier(0);
        if (kt < 10) ISSUE_TILE(kt + 2, (kt + 2) % 3);

        int cur = kt % 3;
        bh8 a[4], b[4];
#pragma unroll
        for (int mf = 0; mf < 4; ++mf)
            a[mf] = *(const bh8*)&Wt[cur][wr * 64 + mf * 16 + li][gsw];
#pragma unroll
        for (int nf = 0; nf < 4; ++nf)
            b[nf] = *(const bh8*)&Yt[cur][wc * 64 + nf * 16 + li][gsw];
#pragma unroll
        for (int mf = 0; mf < 4; ++mf)
#pragma unroll
            for (int nf = 0; nf < 4; ++nf)
                acc[mf][nf] = __builtin_amdgcn_mfma_f32_16x16x32_bf16(
                    a[mf], b[nf], acc[mf][nf], 0, 0, 0);
    }

    // D rows = c, cols = p (lane). fp32 std layout, un-gather windows.
#pragma unroll
    for (int mf = 0; mf < 4; ++mf) {
        int c = cm0 + wr * 64 + mf * 16 + g * 4;
#pragma unroll
        for (int nf = 0; nf < 4; ++nf) {
            int p = pp0 + wc * 64 + nf * 16 + li;
            int n = p / HWP;
            int rem = p - n * HWP;
            int win = rem >> 6, t = rem & 63;
            int h = (win / NWIN) * 8 + (t >> 3);
            int w = (win % NWIN) * 8 + (t & 7);
            float* op = outf + (size_t)n * CCH * HWP + (size_t)h * WWD + w;
            op[(size_t)(c + 0) * HWP] = acc[mf][nf][0] + bv4[mf].x;
            op[(size_t)(c + 1) * HWP] = acc[mf][nf][1] + bv4[mf].y;
            op[(size_t)(c + 2) * HWP] = acc[mf][nf][2] + bv4[mf].z;
            op[(size_t)(c + 3) * HWP] = acc[mf][nf][3] + bv4[mf].w;
        }
    }
}

// ---------------------------------------------------------------------------
// MFMA window attention v4: TWO waves cooperate per (window, head) pair.
// Block = 4 waves = 2 pairs; grid 6912 = 8 x 432 * 2 (bijective XCD swizzle).
// Wave `half` computes QK^T + softmax for tq rows half*32..+31 (8 MFMA),
// writes its P half to the pair's Pl[2][64][72]; one __syncthreads; then PV
// for d rows half*16..+15 reading full P (8 MFMA). Serial chain ~halved.
// ---------------------------------------------------------------------------
__global__ __launch_bounds__(256) void attn(
    const unsigned short* __restrict__ q, const unsigned short* __restrict__ k,
    const unsigned short* __restrict__ v, const float* __restrict__ Bx,
    unsigned short* __restrict__ o)
{
    __shared__ unsigned short Pl[2][64][72];    // full P per pair (18.4 KB)

    int tid = threadIdx.x, lid = tid & 63, wid = tid >> 6;
    int bL = blockIdx.x;
    int b = (bL & 7) * 864 + (bL >> 3);     // bijective XCD swizzle (6912 = 8*864)
    int pl   = wid >> 1;                    // pair slot in block (0,1)
    int half = wid & 1;                     // tq-half for QK^T, d-half for PV
    int pair = b * 2 + pl;                  // 0..13823
    int wl = pair / 12;
    int hq = pair - wl * 12;
    int n = wl / WINS, winl = wl - n * WINS;
    int li = lid & 15, g = lid >> 4;

    const fx4 z = (fx4){0.f, 0.f, 0.f, 0.f};

    const unsigned short* qp = q + (size_t)(wl * 64) * CCH + hq * HD + g * 8;
    const unsigned short* kp = k + (size_t)(wl * 64) * CCH + hq * HD + g * 8;
    bh8 aq[2], bk[4];
#pragma unroll
    for (int mfl = 0; mfl < 2; ++mfl)
        aq[mfl] = *(const bh8*)(qp + (size_t)((half * 2 + mfl) * 16 + li) * CCH);
#pragma unroll
    for (int nf = 0; nf < 4; ++nf)
        bk[nf] = *(const bh8*)(kp + (size_t)(nf * 16 + li) * CCH);

    // hoisted V loads (d rows half*16+li): softmax covers their latency
    bh8 av[2];
#pragma unroll
    for (int ks = 0; ks < 2; ++ks)
        av[ks] = *(const bh8*)(v + (size_t)(n * CCH + hq * HD + half * 16 + li) * HWP
                                 + winl * 64 + ks * 32 + g * 8);

    fx4 s[2][4];
    __builtin_amdgcn_s_setprio(1);
#pragma unroll
    for (int mfl = 0; mfl < 2; ++mfl)
#pragma unroll
        for (int nf = 0; nf < 4; ++nf)
            s[mfl][nf] = __builtin_amdgcn_mfma_f32_16x16x32_bf16(aq[mfl], bk[nf], z, 0, 0, 0);
    __builtin_amdgcn_s_setprio(0);

    // bias: lane-coalesced table, mf = half*2 + mfl
    {
        const float* bxl = Bx + (((size_t)hq * 16 + li) * 4 + g) * 64;
#pragma unroll
        for (int nf = 0; nf < 4; ++nf)
#pragma unroll
            for (int mfl = 0; mfl < 2; ++mfl) {
                fx4 bv = *(const fx4*)&bxl[(nf * 4 + half * 2 + mfl) * 4];
                s[mfl][nf] += bv;
            }
    }

    // softmax across tk (lane group of 16 shares a row set)
    float inv_[2][4];
#pragma unroll
    for (int mfl = 0; mfl < 2; ++mfl)
#pragma unroll
        for (int r = 0; r < 4; ++r) {
            float m = s[mfl][0][r];
#pragma unroll
            for (int nf = 1; nf < 4; ++nf) m = fmaxf(m, s[mfl][nf][r]);
            m = fmaxf(m, __shfl_xor(m, 1));
            m = fmaxf(m, __shfl_xor(m, 2));
            m = fmaxf(m, __shfl_xor(m, 4));
            m = fmaxf(m, __shfl_xor(m, 8));
            float sum = 0.f;
#pragma unroll
            for (int nf = 0; nf < 4; ++nf) {
                float e = __expf(s[mfl][nf][r] - m);
                s[mfl][nf][r] = e;
                sum += e;
            }
            sum += __shfl_xor(sum, 1);
            sum += __shfl_xor(sum, 2);
            sum += __shfl_xor(sum, 4);
            sum += __shfl_xor(sum, 8);
            inv_[mfl][r] = 1.f / sum;
        }

    // write own P half: rows half*32 + mfl*16 + g*4 + r, cols nf*16+li
#pragma unroll
    for (int mfl = 0; mfl < 2; ++mfl)
#pragma unroll
        for (int nf = 0; nf < 4; ++nf)
#pragma unroll
            for (int r = 0; r < 4; ++r)
                Pl[pl][half * 32 + mfl * 16 + g * 4 + r][nf * 16 + li] =
                    f2bf(s[mfl][nf][r] * inv_[mfl][r]);

    __syncthreads();                        // both halves of P visible

    // PV: O^T[d][tq] for d rows half*16..+15, reading full P
    fx4 o2[4];
#pragma unroll
    for (int nf = 0; nf < 4; ++nf) o2[nf] = z;
#pragma unroll
    for (int ks = 0; ks < 2; ++ks) {
        bh8 bp[4];
#pragma unroll
        for (int nfq = 0; nfq < 4; ++nfq)
            bp[nfq] = *(const bh8*)&Pl[pl][nfq * 16 + li][ks * 32 + g * 8];
        __builtin_amdgcn_s_setprio(1);
#pragma unroll
        for (int nfq = 0; nfq < 4; ++nfq)
            o2[nfq] = __builtin_amdgcn_mfma_f32_16x16x32_bf16(
                av[ks], bp[nfq], o2[nfq], 0, 0, 0);
        __builtin_amdgcn_s_setprio(0);
    }

#pragma unroll
    for (int nf = 0; nf < 4; ++nf) {
        int tq = nf * 16 + li;
        int d = hq * HD + half * 16 + g * 4;
        us4 ov;
        ov[0] = f2bf(o2[nf][0]);
        ov[1] = f2bf(o2[nf][1]);
        ov[2] = f2bf(o2[nf][2]);
        ov[3] = f2bf(o2[nf][3]);
        *(us4*)(o + (size_t)(wl * 64 + tq) * CCH + d) = ov;
    }
}

// ---------------------------------------------------------------------------
extern "C" void kernel_launch(void* const* d_in, const int* in_sizes, int n_in,
                              void* d_out, int out_size, void* d_ws, size_t ws_size,
                              hipStream_t stream) {
    const float* vid  = (const float*)d_in[0];
    const float* qd_w = (const float*)d_in[1];
    const float* qd_b = (const float*)d_in[2];
    const float* qp_w = (const float*)d_in[3];
    const float* qp_b = (const float*)d_in[4];
    const float* kd_w = (const float*)d_in[5];
    const float* kd_b = (const float*)d_in[6];
    const float* kp_w = (const float*)d_in[7];
    const float* kp_b = (const float*)d_in[8];
    const float* vd_w = (const float*)d_in[9];
    const float* vd_b = (const float*)d_in[10];
    const float* vp_w = (const float*)d_in[11];
    const float* vp_b = (const float*)d_in[12];
    const float* rpb  = (const float*)d_in[13];
    const float* pj_w = (const float*)d_in[14];
    const float* pj_b = (const float*)d_in[15];

    unsigned short* ws16 = (unsigned short*)d_ws;
    unsigned short* tr0 = ws16 + 3 * EELEM;     // [p_wg][c] bf16 (q,k,v pre-GEMM)
    unsigned short* tr1 = ws16 + 4 * EELEM;
    unsigned short* tr2 = ws16 + 5 * EELEM;
    unsigned short* Wb  = ws16 + 6 * EELEM;     // 4 x 147456 bf16
    float* dwT          = (float*)(Wb + 4 * WMAT);      // [3][9][384] fp32
    float* Bx           = dwT + 3 * 9 * CCH;            // [12][16][4][4][4][4] fp32
    unsigned short* qb  = ws16;                 // post-GEMM q,k,v
    unsigned short* kb  = ws16 + EELEM;
    unsigned short* vb  = ws16 + 2 * EELEM;
    unsigned short* ob  = tr0;                  // attn out reuses tr region

    prep<<<521, 256, 0, stream>>>(qp_w, kp_w, vp_w, pj_w,
                                  qd_w, kd_w, vd_w, rpb, Wb, dwT, Bx);
    dwgather<<<NIMG * WINS * 6, 256, 0, stream>>>(
        vid, dwT, qd_b, kd_b, vd_b, tr0, tr1, tr2);

    const float scale = 0.17677669529663687f;   // 32^-0.5 folded into q
    qkv_gemm<<<5184, 256, 0, stream>>>(
        tr0, tr1, tr2, Wb, qp_b, kp_b, vp_b, scale, qb, kb, vb);

    attn<<<6912, 256, 0, stream>>>(qb, kb, vb, Bx, ob);

    proj_gemm<<<1728, 256, 0, stream>>>(
        ob, Wb + 3 * WMAT, pj_b, (float*)d_out);
}